// Round 1
// baseline (398.001 us; speedup 1.0000x reference)
//
#include <hip/hip_runtime.h>

#define B_    8
#define C_    1024
#define HID   64
#define N_    2048
#define RTOT  192   // 64 theta + 64 phi + 64 g rows

// ---------------- workspace layout (float offsets) ----------------
#define OFF_TPG 0                       // [B][192][N]   theta/phi/g projections
#define OFF_M   (B_*RTOT*N_)            // [B][64][64]   M = phi · g^T
#define OFF_G   (OFF_M + B_*HID*HID)    // [B][64][64]   G = theta · theta^T
#define OFF_S   (OFF_G + B_*HID*HID)    // [B][64]       S_e = sum_n theta
#define OFF_WM  (OFF_S + B_*HID)        // [B][1024][64] Wm = w_w·M^T / N
#define OFF_SC  (OFF_WM + B_*C_*HID)    // [1024] BN scale
#define OFF_SH  (OFF_SC + C_)           // [1024] BN shift (w_b folded)

// K1: fused projection GEMM: tpg[b][r][n] = Wcat[r,:]·x[b,:,n] + bcat[r]
__global__ __launch_bounds__(256) void proj_gemm(
    const float* __restrict__ x,
    const float* __restrict__ tw, const float* __restrict__ tb,
    const float* __restrict__ pw, const float* __restrict__ pb,
    const float* __restrict__ gw, const float* __restrict__ gb,
    float* __restrict__ tpg)
{
    const int b = blockIdx.z, rt = blockIdx.y, nt = blockIdx.x;
    const int r0 = rt * 64, n0 = nt * 128;
    const int t = threadIdx.x;
    __shared__ float As[32][68];    // [k][m], pad 4 keeps 16B alignment
    __shared__ float Bs[32][128];   // [k][n]

    float acc[8][4];
#pragma unroll
    for (int i = 0; i < 8; i++)
#pragma unroll
        for (int j = 0; j < 4; j++) acc[i][j] = 0.f;

    const int tm = t >> 5, tn = t & 31;
    const int am = t >> 2;          // 0..63 output row within tile
    const int ak = (t & 3) * 8;     // k-subgroup 0/8/16/24
    const int rg = r0 + am;
    const float* wrow;
    if (rg < 64)        wrow = tw + (size_t)rg * 1024;
    else if (rg < 128)  wrow = pw + (size_t)(rg - 64) * 1024;
    else                wrow = gw + (size_t)(rg - 128) * 1024;
    const float* xb = x + (size_t)b * C_ * N_;

    for (int k0 = 0; k0 < 1024; k0 += 32) {
        float4 w0 = *(const float4*)(wrow + k0 + ak);
        float4 w1 = *(const float4*)(wrow + k0 + ak + 4);
        As[ak + 0][am] = w0.x; As[ak + 1][am] = w0.y;
        As[ak + 2][am] = w0.z; As[ak + 3][am] = w0.w;
        As[ak + 4][am] = w1.x; As[ak + 5][am] = w1.y;
        As[ak + 6][am] = w1.z; As[ak + 7][am] = w1.w;
#pragma unroll
        for (int i = 0; i < 4; i++) {
            int f = t + i * 256;
            int kk = f >> 5, c4 = f & 31;
            *(float4*)&Bs[kk][c4 * 4] =
                *(const float4*)(xb + (size_t)(k0 + kk) * N_ + n0 + c4 * 4);
        }
        __syncthreads();
#pragma unroll
        for (int kk = 0; kk < 32; kk++) {
            float4 a0 = *(const float4*)&As[kk][tm * 8];
            float4 a1 = *(const float4*)&As[kk][tm * 8 + 4];
            float4 b0 = *(const float4*)&Bs[kk][tn * 4];
            float a[8] = {a0.x, a0.y, a0.z, a0.w, a1.x, a1.y, a1.z, a1.w};
            float bb[4] = {b0.x, b0.y, b0.z, b0.w};
#pragma unroll
            for (int i = 0; i < 8; i++)
#pragma unroll
                for (int j = 0; j < 4; j++)
                    acc[i][j] = fmaf(a[i], bb[j], acc[i][j]);
        }
        __syncthreads();
    }
#pragma unroll
    for (int i = 0; i < 8; i++) {
        int r = r0 + tm * 8 + i;
        float bias = (r < 64) ? tb[r] : (r < 128 ? pb[r - 64] : gb[r - 128]);
        float4 o;
        o.x = acc[i][0] + bias; o.y = acc[i][1] + bias;
        o.z = acc[i][2] + bias; o.w = acc[i][3] + bias;
        *(float4*)(tpg + ((size_t)b * RTOT + r) * N_ + n0 + tn * 4) = o;
    }
}

// K2: 64x64 gram products over N (k-split + atomics).
// p==0: M = phi · g^T ; p==1: G = theta · theta^T
__global__ __launch_bounds__(256) void gram64(
    const float* __restrict__ tpg, float* __restrict__ Mout, float* __restrict__ Gout)
{
    const int kc = blockIdx.x;   // 32 chunks of 64 along N
    const int p  = blockIdx.y;
    const int b  = blockIdx.z;
    const int n0 = kc * 64;
    __shared__ float As2[64][65];
    __shared__ float Bs2[64][65];
    const int t = threadIdx.x;
    const float* base  = tpg + (size_t)b * RTOT * N_;
    const float* Aglob = base + (p == 0 ? (size_t)64 * N_ : 0);
    const float* Bglob = base + (p == 0 ? (size_t)128 * N_ : 0);
    float* outp = (p == 0 ? Mout : Gout) + (size_t)b * HID * HID;

#pragma unroll
    for (int i = 0; i < 4; i++) {
        int f = t + i * 256;
        int e = f >> 4, n4 = f & 15;
        float4 va = *(const float4*)(Aglob + (size_t)e * N_ + n0 + n4 * 4);
        As2[e][n4 * 4 + 0] = va.x; As2[e][n4 * 4 + 1] = va.y;
        As2[e][n4 * 4 + 2] = va.z; As2[e][n4 * 4 + 3] = va.w;
        float4 vb = *(const float4*)(Bglob + (size_t)e * N_ + n0 + n4 * 4);
        Bs2[e][n4 * 4 + 0] = vb.x; Bs2[e][n4 * 4 + 1] = vb.y;
        Bs2[e][n4 * 4 + 2] = vb.z; Bs2[e][n4 * 4 + 3] = vb.w;
    }
    __syncthreads();
    const int e  = t & 63;
    const int d0 = (t >> 6) * 16;
    float acc[16];
#pragma unroll
    for (int j = 0; j < 16; j++) acc[j] = 0.f;
    for (int nn = 0; nn < 64; nn++) {
        float a = As2[e][nn];
#pragma unroll
        for (int j = 0; j < 16; j++) acc[j] = fmaf(a, Bs2[d0 + j][nn], acc[j]);
    }
#pragma unroll
    for (int j = 0; j < 16; j++) atomicAdd(outp + e * HID + d0 + j, acc[j]);
}

// K3: S[b][e] = sum_n theta[b][e][n]
__global__ __launch_bounds__(64) void rowsum(const float* __restrict__ tpg, float* __restrict__ S)
{
    const int e = blockIdx.x, b = blockIdx.y, lane = threadIdx.x;
    const float* p = tpg + ((size_t)b * RTOT + e) * N_;
    float v = 0.f;
    for (int i = lane; i < N_; i += 64) v += p[i];
    for (int off = 32; off; off >>= 1) v += __shfl_down(v, off);
    if (lane == 0) S[b * HID + e] = v;
}

// K4: Wm[b][c][e] = (1/N) * sum_d w_w[c][d] * M[b][e][d]
__global__ __launch_bounds__(64) void wmk(
    const float* __restrict__ ww, const float* __restrict__ Mm, float* __restrict__ Wm)
{
    const int c = blockIdx.x, b = blockIdx.y, e = threadIdx.x;
    const float* wr = ww + (size_t)c * HID;
    const float* mr = Mm + (size_t)b * HID * HID + (size_t)e * HID;
    float acc = 0.f;
#pragma unroll
    for (int d = 0; d < HID; d += 4) {
        float4 w4 = *(const float4*)(wr + d);
        float4 m4 = *(const float4*)(mr + d);
        acc += w4.x * m4.x + w4.y * m4.y + w4.z * m4.z + w4.w * m4.w;
    }
    Wm[((size_t)b * C_ + c) * HID + e] = acc * (1.0f / N_);
}

// K5: exact BN stats via Gram trick; emit scale/shift (w_b folded into shift)
__global__ __launch_bounds__(64) void statsk(
    const float* __restrict__ Wm, const float* __restrict__ S, const float* __restrict__ G,
    const float* __restrict__ wb, const float* __restrict__ gamma, const float* __restrict__ beta,
    float* __restrict__ scale, float* __restrict__ shift2)
{
    const int c = blockIdx.x, lane = threadIdx.x;
    const float wbc = wb[c];
    float asum = 0.f, asq = 0.f;
    for (int b = 0; b < B_; b++) {
        float v  = Wm[((size_t)b * C_ + c) * HID + lane];
        float sv = S[b * HID + lane];
        float t1 = v * sv;
        for (int off = 32; off; off >>= 1) t1 += __shfl_down(t1, off);
        t1 = __shfl(t1, 0);
        const float* Gb = G + (size_t)b * HID * HID + (size_t)lane * HID;
        float inner = 0.f;
        for (int f = 0; f < HID; f++) inner = fmaf(Gb[f], __shfl(v, f), inner);
        float q = v * inner;
        for (int off = 32; off; off >>= 1) q += __shfl_down(q, off);
        q = __shfl(q, 0);
        asum += t1;
        asq  += q + 2.f * wbc * t1;
    }
    const float cnt = (float)B_ * (float)N_;
    const float inv = 1.0f / cnt;
    float mean = (asum + cnt * wbc) * inv;
    float e2   = (asq + cnt * wbc * wbc) * inv;
    float var  = e2 - mean * mean;
    float sc   = gamma[c] * rsqrtf(var + 1e-5f);
    if (lane == 0) {
        scale[c]  = sc;
        shift2[c] = beta[c] - mean * sc + sc * wbc;
    }
}

// K6: out[b][c][n] = scale[c]*(Wm[b][c][:]·theta[b][:][n]) + shift2[c] + x[b][c][n]
__global__ __launch_bounds__(256) void finalk(
    const float* __restrict__ Wm, const float* __restrict__ tpg,
    const float* __restrict__ x, const float* __restrict__ scale,
    const float* __restrict__ shift2, float* __restrict__ out)
{
    const int nt = blockIdx.x, ct = blockIdx.y, b = blockIdx.z;
    const int n0 = nt * 128, c0 = ct * 64;
    const int t = threadIdx.x;
    __shared__ float Wms[64][68];   // [e][c]
    __shared__ float Ts[64][128];   // [e][n]

#pragma unroll
    for (int i = 0; i < 4; i++) {
        int f = t + i * 256;
        int cc = f >> 4, e4 = f & 15;
        float4 v = *(const float4*)(Wm + ((size_t)b * C_ + c0 + cc) * HID + e4 * 4);
        Wms[e4 * 4 + 0][cc] = v.x; Wms[e4 * 4 + 1][cc] = v.y;
        Wms[e4 * 4 + 2][cc] = v.z; Wms[e4 * 4 + 3][cc] = v.w;
    }
    const float* Tb = tpg + (size_t)b * RTOT * N_;
#pragma unroll
    for (int i = 0; i < 8; i++) {
        int f = t + i * 256;
        int e = f >> 5, c4 = f & 31;
        *(float4*)&Ts[e][c4 * 4] = *(const float4*)(Tb + (size_t)e * N_ + n0 + c4 * 4);
    }
    __syncthreads();

    const int tm = t >> 5, tn = t & 31;
    float acc[8][4];
#pragma unroll
    for (int i = 0; i < 8; i++)
#pragma unroll
        for (int j = 0; j < 4; j++) acc[i][j] = 0.f;

#pragma unroll
    for (int e = 0; e < 64; e++) {
        float4 a0 = *(const float4*)&Wms[e][tm * 8];
        float4 a1 = *(const float4*)&Wms[e][tm * 8 + 4];
        float4 b0 = *(const float4*)&Ts[e][tn * 4];
        float a[8] = {a0.x, a0.y, a0.z, a0.w, a1.x, a1.y, a1.z, a1.w};
        float bb[4] = {b0.x, b0.y, b0.z, b0.w};
#pragma unroll
        for (int i = 0; i < 8; i++)
#pragma unroll
            for (int j = 0; j < 4; j++)
                acc[i][j] = fmaf(a[i], bb[j], acc[i][j]);
    }
#pragma unroll
    for (int i = 0; i < 8; i++) {
        int c = c0 + tm * 8 + i;
        float sc = scale[c], sh = shift2[c];
        size_t off = ((size_t)b * C_ + c) * N_ + n0 + tn * 4;
        float4 xv = *(const float4*)(x + off);
        float4 o;
        o.x = fmaf(sc, acc[i][0], sh) + xv.x;
        o.y = fmaf(sc, acc[i][1], sh) + xv.y;
        o.z = fmaf(sc, acc[i][2], sh) + xv.z;
        o.w = fmaf(sc, acc[i][3], sh) + xv.w;
        *(float4*)(out + off) = o;
    }
}

extern "C" void kernel_launch(void* const* d_in, const int* in_sizes, int n_in,
                              void* d_out, int out_size, void* d_ws, size_t ws_size,
                              hipStream_t stream)
{
    const float* x  = (const float*)d_in[0];
    const float* tw = (const float*)d_in[1];
    const float* tb = (const float*)d_in[2];
    const float* pw = (const float*)d_in[3];
    const float* pb = (const float*)d_in[4];
    const float* gw = (const float*)d_in[5];
    const float* gb = (const float*)d_in[6];
    const float* ww = (const float*)d_in[7];
    const float* wb = (const float*)d_in[8];
    const float* gamma = (const float*)d_in[9];
    const float* beta  = (const float*)d_in[10];
    float* out = (float*)d_out;

    float* ws   = (float*)d_ws;
    float* tpg  = ws + OFF_TPG;
    float* Mm   = ws + OFF_M;
    float* Gg   = ws + OFF_G;
    float* S    = ws + OFF_S;
    float* Wm   = ws + OFF_WM;
    float* scl  = ws + OFF_SC;
    float* shf  = ws + OFF_SH;

    // zero the atomic accumulators (M and G are contiguous)
    hipMemsetAsync(Mm, 0, (size_t)2 * B_ * HID * HID * sizeof(float), stream);

    proj_gemm<<<dim3(16, 3, B_), 256, 0, stream>>>(x, tw, tb, pw, pb, gw, gb, tpg);
    gram64<<<dim3(32, 2, B_), 256, 0, stream>>>(tpg, Mm, Gg);
    rowsum<<<dim3(HID, B_), 64, 0, stream>>>(tpg, S);
    wmk<<<dim3(C_, B_), 64, 0, stream>>>(ww, Mm, Wm);
    statsk<<<C_, 64, 0, stream>>>(Wm, S, Gg, wb, gamma, beta, scl, shf);
    finalk<<<dim3(16, 16, B_), 256, 0, stream>>>(Wm, tpg, x, scl, shf, out);
}

// Round 2
// 248.640 us; speedup vs baseline: 1.6007x; 1.6007x over previous
//
#include <hip/hip_runtime.h>

#define B_    8
#define C_    1024
#define HID   64
#define N_    2048
#define RTOT  192

typedef __attribute__((ext_vector_type(8))) short   bf16x8;
typedef __attribute__((ext_vector_type(8))) unsigned short ush8;
typedef __attribute__((ext_vector_type(4))) float   f32x4;

// ---- workspace byte offsets (all 256-B aligned) ----
#define WSB_XT    ((size_t)0)          // [B][2048][1024] bf16  (x transposed)   33,554,432 B
#define WSB_WBF   ((size_t)33554432)   // [192][1024]     bf16  (concat weights)    393,216 B
#define WSB_TPG   ((size_t)33947648)   // [B][192][2048]  bf16  (theta/phi/g)     6,291,456 B
#define WSB_THT   ((size_t)40239104)   // [B][2048][64]   bf16  (theta^T)         2,097,152 B
#define WSB_M     ((size_t)42336256)   // [B][64][64]     f32                       131,072 B
#define WSB_G     ((size_t)42467328)   // [B][64][64]     f32                       131,072 B
#define WSB_S     ((size_t)42598400)   // [B][64]         f32                         2,048 B
#define WSB_WMBF  ((size_t)42600448)   // [B][1024][64]   bf16  (Wm)              1,048,576 B
#define WSB_SC    ((size_t)43649024)   // [1024] f32
#define WSB_SH    ((size_t)43653120)   // [1024] f32

static __device__ __forceinline__ unsigned short f2bf(float f) {
    union { float f; unsigned u; } v; v.f = f;
    unsigned r = v.u + 0x7fffu + ((v.u >> 16) & 1u);
    return (unsigned short)(r >> 16);
}
static __device__ __forceinline__ float bf2f(unsigned short h) {
    union { unsigned u; float f; } v; v.u = ((unsigned)h) << 16;
    return v.f;
}

// K0: convert concatenated weights (theta/phi/g) to bf16
__global__ __launch_bounds__(256) void wcvt(
    const float* __restrict__ tw, const float* __restrict__ pw,
    const float* __restrict__ gw, unsigned short* __restrict__ wbf)
{
    int idx = blockIdx.x * 256 + threadIdx.x;          // < 192*1024
    int r = idx >> 10, k = idx & 1023;
    float v = (r < 64) ? tw[(size_t)r * 1024 + k]
            : (r < 128) ? pw[(size_t)(r - 64) * 1024 + k]
                        : gw[(size_t)(r - 128) * 1024 + k];
    wbf[idx] = f2bf(v);
}

// K1: x [b][c][n] f32 -> xT [b][n][c] bf16
__global__ __launch_bounds__(256) void xT_k(
    const float* __restrict__ x, unsigned short* __restrict__ xT)
{
    const int b = blockIdx.z, c0 = blockIdx.y * 64, n0 = blockIdx.x * 64;
    const int t = threadIdx.x;
    __shared__ float Ls[64][65];
    const float* xb = x + ((size_t)b * C_ + c0) * N_ + n0;
#pragma unroll
    for (int i = 0; i < 4; i++) {
        int cc = (t >> 4) + 16 * i, n4 = (t & 15) * 4;
        float4 v = *(const float4*)(xb + (size_t)cc * N_ + n4);
        Ls[cc][n4 + 0] = v.x; Ls[cc][n4 + 1] = v.y;
        Ls[cc][n4 + 2] = v.z; Ls[cc][n4 + 3] = v.w;
    }
    __syncthreads();
    const int n = t >> 2, ce = (t & 3) * 16;
    ush8 o0, o1;
#pragma unroll
    for (int j = 0; j < 8; j++) o0[j] = f2bf(Ls[ce + j][n]);
#pragma unroll
    for (int j = 0; j < 8; j++) o1[j] = f2bf(Ls[ce + 8 + j][n]);
    unsigned short* dst = xT + ((size_t)b * N_ + n0 + n) * C_ + c0 + ce;
    *(ush8*)dst = o0;
    *(ush8*)(dst + 8) = o1;
}

// K2: MFMA projections: tpgbf[b][r][n] = bf16( Wcat[r,:]·x[b,:,n] + bias[r] )
__global__ __launch_bounds__(256) void proj_mfma(
    const unsigned short* __restrict__ xT, const unsigned short* __restrict__ wbf,
    const float* __restrict__ tb, const float* __restrict__ pb,
    const float* __restrict__ gb, unsigned short* __restrict__ tpgbf)
{
    const int b = blockIdx.y, n0 = blockIdx.x * 32;
    const int t = threadIdx.x, w = t >> 6, L = t & 63;
    const int lr = L & 15, q = L >> 4;

    const unsigned short* ap = wbf + ((size_t)(48 * w + lr)) * 1024 + q * 8;
    const unsigned short* bp = xT + ((size_t)b * N_ + n0 + lr) * 1024 + q * 8;

    f32x4 acc[3][2] = {};
#pragma unroll 2
    for (int k0 = 0; k0 < 1024; k0 += 32) {
        bf16x8 A0 = *(const bf16x8*)(ap + k0);
        bf16x8 A1 = *(const bf16x8*)(ap + 16 * 1024 + k0);
        bf16x8 A2 = *(const bf16x8*)(ap + 32 * 1024 + k0);
        bf16x8 B0 = *(const bf16x8*)(bp + k0);
        bf16x8 B1 = *(const bf16x8*)(bp + 16 * 1024 + k0);
        acc[0][0] = __builtin_amdgcn_mfma_f32_16x16x32_bf16(A0, B0, acc[0][0], 0, 0, 0);
        acc[0][1] = __builtin_amdgcn_mfma_f32_16x16x32_bf16(A0, B1, acc[0][1], 0, 0, 0);
        acc[1][0] = __builtin_amdgcn_mfma_f32_16x16x32_bf16(A1, B0, acc[1][0], 0, 0, 0);
        acc[1][1] = __builtin_amdgcn_mfma_f32_16x16x32_bf16(A1, B1, acc[1][1], 0, 0, 0);
        acc[2][0] = __builtin_amdgcn_mfma_f32_16x16x32_bf16(A2, B0, acc[2][0], 0, 0, 0);
        acc[2][1] = __builtin_amdgcn_mfma_f32_16x16x32_bf16(A2, B1, acc[2][1], 0, 0, 0);
    }
#pragma unroll
    for (int f = 0; f < 3; f++)
#pragma unroll
        for (int r = 0; r < 4; r++) {
            int row = 48 * w + 16 * f + q * 4 + r;
            float bias = (row < 64) ? tb[row] : (row < 128) ? pb[row - 64] : gb[row - 128];
#pragma unroll
            for (int g = 0; g < 2; g++) {
                int col = n0 + 16 * g + lr;
                tpgbf[((size_t)b * RTOT + row) * N_ + col] = f2bf(acc[f][g][r] + bias);
            }
        }
}

// K3: gram products via MFMA, K-split with atomics.
// p==0: M[e][d]=sum_n phi[e][n]g[d][n];  p==1: G[e][f]=sum_n theta[e][n]theta[f][n]
__global__ __launch_bounds__(256) void gram_mfma(
    const unsigned short* __restrict__ tpgbf, float* __restrict__ Mm, float* __restrict__ Gg)
{
    const int kc = blockIdx.x, p = blockIdx.y, b = blockIdx.z;
    const int t = threadIdx.x, w = t >> 6, L = t & 63;
    const int lr = L & 15, q = L >> 4;
    const unsigned short* base = tpgbf + (size_t)b * RTOT * N_;
    const unsigned short* Arow = base + (p ? 0 : (size_t)64 * N_);    // theta or phi
    const unsigned short* Brow = base + (p ? 0 : (size_t)128 * N_);   // theta or g
    const unsigned short* ap = Arow + ((size_t)(16 * w + lr)) * N_ + kc * 512 + q * 8;
    const unsigned short* bp = Brow + ((size_t)lr) * N_ + kc * 512 + q * 8;

    f32x4 acc[4] = {};
#pragma unroll 2
    for (int k0 = 0; k0 < 512; k0 += 32) {
        bf16x8 A = *(const bf16x8*)(ap + k0);
#pragma unroll
        for (int g = 0; g < 4; g++) {
            bf16x8 B = *(const bf16x8*)(bp + (size_t)g * 16 * N_ + k0);
            acc[g] = __builtin_amdgcn_mfma_f32_16x16x32_bf16(A, B, acc[g], 0, 0, 0);
        }
    }
    float* outp = (p ? Gg : Mm) + (size_t)b * HID * HID;
#pragma unroll
    for (int g = 0; g < 4; g++)
#pragma unroll
        for (int r = 0; r < 4; r++) {
            int row = 16 * w + q * 4 + r, col = 16 * g + lr;
            atomicAdd(outp + row * HID + col, acc[g][r]);
        }
}

// K4: S[b][e] = sum_n theta_bf16[b][e][n]
__global__ __launch_bounds__(64) void rowsum_bf(
    const unsigned short* __restrict__ tpgbf, float* __restrict__ S)
{
    const int e = blockIdx.x, b = blockIdx.y, lane = threadIdx.x;
    const unsigned short* p = tpgbf + ((size_t)b * RTOT + e) * N_;
    float v = 0.f;
    for (int i = lane * 8; i < N_; i += 64 * 8) {
        ush8 u = *(const ush8*)(p + i);
#pragma unroll
        for (int j = 0; j < 8; j++) v += bf2f(u[j]);
    }
    for (int off = 32; off; off >>= 1) v += __shfl_down(v, off);
    if (lane == 0) S[b * HID + e] = v;
}

// K5: theta [e][n] bf16 -> thT [b][n][64] bf16
__global__ __launch_bounds__(256) void thT_k(
    const unsigned short* __restrict__ tpgbf, unsigned short* __restrict__ thT)
{
    const int b = blockIdx.y, n0 = blockIdx.x * 64;
    const int t = threadIdx.x;
    __shared__ unsigned short Ls[64][70];
    const unsigned short* src = tpgbf + (size_t)b * RTOT * N_ + n0;
    {
        int e = t >> 2, nc = (t & 3) * 16;
        ush8 v0 = *(const ush8*)(src + (size_t)e * N_ + nc);
        ush8 v1 = *(const ush8*)(src + (size_t)e * N_ + nc + 8);
#pragma unroll
        for (int j = 0; j < 8; j++) Ls[e][nc + j] = v0[j];
#pragma unroll
        for (int j = 0; j < 8; j++) Ls[e][nc + 8 + j] = v1[j];
    }
    __syncthreads();
    const int n = t >> 2, ec = (t & 3) * 16;
    ush8 o0, o1;
#pragma unroll
    for (int j = 0; j < 8; j++) o0[j] = Ls[ec + j][n];
#pragma unroll
    for (int j = 0; j < 8; j++) o1[j] = Ls[ec + 8 + j][n];
    unsigned short* dst = thT + ((size_t)b * N_ + n0 + n) * HID + ec;
    *(ush8*)dst = o0;
    *(ush8*)(dst + 8) = o1;
}

// K6: wmbf[b][c][e] = bf16( (1/N) sum_d ww[c][d] * M[b][e][d] )
__global__ __launch_bounds__(64) void wmk(
    const float* __restrict__ ww, const float* __restrict__ Mm,
    unsigned short* __restrict__ wmbf)
{
    const int c = blockIdx.x, b = blockIdx.y, e = threadIdx.x;
    const float* wr = ww + (size_t)c * HID;
    const float* mr = Mm + (size_t)b * HID * HID + (size_t)e * HID;
    float acc = 0.f;
#pragma unroll
    for (int d = 0; d < HID; d += 4) {
        float4 w4 = *(const float4*)(wr + d);
        float4 m4 = *(const float4*)(mr + d);
        acc += w4.x * m4.x + w4.y * m4.y + w4.z * m4.z + w4.w * m4.w;
    }
    wmbf[((size_t)b * C_ + c) * HID + e] = f2bf(acc * (1.0f / N_));
}

// K7: exact BN stats from the SAME bf16 operands finalk uses
__global__ __launch_bounds__(64) void statsk(
    const unsigned short* __restrict__ wmbf, const float* __restrict__ S,
    const float* __restrict__ G, const float* __restrict__ wb,
    const float* __restrict__ gamma, const float* __restrict__ beta,
    float* __restrict__ scale, float* __restrict__ shift2)
{
    const int c = blockIdx.x, lane = threadIdx.x;
    const float wbc = wb[c];
    float asum = 0.f, asq = 0.f;
    for (int b = 0; b < B_; b++) {
        float v  = bf2f(wmbf[((size_t)b * C_ + c) * HID + lane]);
        float sv = S[b * HID + lane];
        float t1 = v * sv;
        for (int off = 32; off; off >>= 1) t1 += __shfl_down(t1, off);
        t1 = __shfl(t1, 0);
        const float* Gb = G + (size_t)b * HID * HID + (size_t)lane * HID;
        float inner = 0.f;
        for (int f = 0; f < HID; f++) inner = fmaf(Gb[f], __shfl(v, f), inner);
        float q = v * inner;
        for (int off = 32; off; off >>= 1) q += __shfl_down(q, off);
        q = __shfl(q, 0);
        asum += t1;
        asq  += q + 2.f * wbc * t1;
    }
    const float cnt = (float)B_ * (float)N_;
    const float inv = 1.0f / cnt;
    float mean = (asum + cnt * wbc) * inv;
    float e2   = (asq + cnt * wbc * wbc) * inv;
    float var  = e2 - mean * mean;
    float sc   = gamma[c] * rsqrtf(var + 1e-5f);
    if (lane == 0) {
        scale[c]  = sc;
        shift2[c] = beta[c] - mean * sc + sc * wbc;
    }
}

// K8: out = scale[c]*(wmbf[b][c][:]·theta[:,n]) + shift[c] + x
__global__ __launch_bounds__(256) void finalk_mfma(
    const unsigned short* __restrict__ wmbf, const unsigned short* __restrict__ thT,
    const float* __restrict__ x, const float* __restrict__ scale,
    const float* __restrict__ shift2, float* __restrict__ out)
{
    const int b = blockIdx.z, c0 = blockIdx.y * 64, n0 = blockIdx.x * 64;
    const int t = threadIdx.x, w = t >> 6, L = t & 63;
    const int lr = L & 15, q = L >> 4;
    const unsigned short* ap = wmbf + ((size_t)b * C_ + c0 + 16 * w + lr) * HID + q * 8;
    const unsigned short* bp = thT + ((size_t)b * N_ + n0 + lr) * HID + q * 8;

    f32x4 acc[4] = {};
#pragma unroll
    for (int k0 = 0; k0 < 64; k0 += 32) {
        bf16x8 A = *(const bf16x8*)(ap + k0);
#pragma unroll
        for (int g = 0; g < 4; g++) {
            bf16x8 B = *(const bf16x8*)(bp + (size_t)g * 16 * HID + k0);
            acc[g] = __builtin_amdgcn_mfma_f32_16x16x32_bf16(A, B, acc[g], 0, 0, 0);
        }
    }
#pragma unroll
    for (int r = 0; r < 4; r++) {
        int c = c0 + 16 * w + q * 4 + r;
        float sc = scale[c], sh = shift2[c];
#pragma unroll
        for (int g = 0; g < 4; g++) {
            int col = n0 + 16 * g + lr;
            size_t off = ((size_t)b * C_ + c) * N_ + col;
            out[off] = fmaf(sc, acc[g][r], sh) + x[off];
        }
    }
}

extern "C" void kernel_launch(void* const* d_in, const int* in_sizes, int n_in,
                              void* d_out, int out_size, void* d_ws, size_t ws_size,
                              hipStream_t stream)
{
    const float* x  = (const float*)d_in[0];
    const float* tw = (const float*)d_in[1];
    const float* tb = (const float*)d_in[2];
    const float* pw = (const float*)d_in[3];
    const float* pb = (const float*)d_in[4];
    const float* gw = (const float*)d_in[5];
    const float* gb = (const float*)d_in[6];
    const float* ww = (const float*)d_in[7];
    const float* wb = (const float*)d_in[8];
    const float* gamma = (const float*)d_in[9];
    const float* beta  = (const float*)d_in[10];
    float* out = (float*)d_out;

    char* ws = (char*)d_ws;
    unsigned short* xT    = (unsigned short*)(ws + WSB_XT);
    unsigned short* wbf   = (unsigned short*)(ws + WSB_WBF);
    unsigned short* tpgbf = (unsigned short*)(ws + WSB_TPG);
    unsigned short* thT   = (unsigned short*)(ws + WSB_THT);
    float* Mm   = (float*)(ws + WSB_M);
    float* Gg   = (float*)(ws + WSB_G);
    float* S    = (float*)(ws + WSB_S);
    unsigned short* wmbf = (unsigned short*)(ws + WSB_WMBF);
    float* scl  = (float*)(ws + WSB_SC);
    float* shf  = (float*)(ws + WSB_SH);

    hipMemsetAsync(Mm, 0, (size_t)2 * B_ * HID * HID * sizeof(float), stream);

    wcvt<<<dim3(RTOT * 1024 / 256), 256, 0, stream>>>(tw, pw, gw, wbf);
    xT_k<<<dim3(32, 16, B_), 256, 0, stream>>>(x, xT);
    proj_mfma<<<dim3(64, B_), 256, 0, stream>>>(xT, wbf, tb, pb, gb, tpgbf);
    gram_mfma<<<dim3(4, 2, B_), 256, 0, stream>>>(tpgbf, Mm, Gg);
    rowsum_bf<<<dim3(HID, B_), 64, 0, stream>>>(tpgbf, S);
    thT_k<<<dim3(32, B_), 256, 0, stream>>>(tpgbf, thT);
    wmk<<<dim3(C_, B_), 64, 0, stream>>>(ww, Mm, wmbf);
    statsk<<<C_, 64, 0, stream>>>(wmbf, S, Gg, wb, gamma, beta, scl, shf);
    finalk_mfma<<<dim3(32, 16, B_), 256, 0, stream>>>(wmbf, thT, x, scl, shf, out);
}

// Round 3
// 243.418 us; speedup vs baseline: 1.6351x; 1.0215x over previous
//
#include <hip/hip_runtime.h>

#define B_    8
#define C_    1024
#define HID   64
#define N_    2048
#define RTOT  192

typedef __attribute__((ext_vector_type(8))) short   bf16x8;
typedef __attribute__((ext_vector_type(8))) unsigned short ush8;
typedef __attribute__((ext_vector_type(4))) unsigned short ush4;
typedef __attribute__((ext_vector_type(4))) float   f32x4;

// ---- workspace byte offsets (all 256-B aligned) ----
#define WSB_XT    ((size_t)0)          // [B][2048][1024] bf16  (x transposed)
#define WSB_WBF   ((size_t)33554432)   // [192][1024]     bf16  (concat weights)
#define WSB_TPG   ((size_t)33947648)   // [B][192][2048]  bf16  (theta/phi/g)
#define WSB_THT   ((size_t)40239104)   // [B][2048][64]   bf16  (theta^T)
#define WSB_M     ((size_t)42336256)   // [B][64][64]     f32
#define WSB_G     ((size_t)42467328)   // [B][64][64]     f32
#define WSB_S     ((size_t)42598400)   // [B][64]         f32   (contiguous after G)
#define WSB_WMBF  ((size_t)42600448)   // [B][1024][64]   bf16  (Wm)
#define WSB_SC    ((size_t)43649024)   // [1024] f32
#define WSB_SH    ((size_t)43653120)   // [1024] f32

static __device__ __forceinline__ unsigned short f2bf(float f) {
    union { float f; unsigned u; } v; v.f = f;
    unsigned r = v.u + 0x7fffu + ((v.u >> 16) & 1u);
    return (unsigned short)(r >> 16);
}
static __device__ __forceinline__ float bf2f(unsigned short h) {
    union { unsigned u; float f; } v; v.u = ((unsigned)h) << 16;
    return v.f;
}

// K0: weights -> bf16 (concat theta/phi/g)
__global__ __launch_bounds__(256) void wcvt(
    const float* __restrict__ tw, const float* __restrict__ pw,
    const float* __restrict__ gw, unsigned short* __restrict__ wbf)
{
    int idx = blockIdx.x * 256 + threadIdx.x;
    int r = idx >> 10, k = idx & 1023;
    float v = (r < 64) ? tw[(size_t)r * 1024 + k]
            : (r < 128) ? pw[(size_t)(r - 64) * 1024 + k]
                        : gw[(size_t)(r - 128) * 1024 + k];
    wbf[idx] = f2bf(v);
}

// K1: x [b][c][n] f32 -> xT [b][n][c] bf16
__global__ __launch_bounds__(256) void xT_k(
    const float* __restrict__ x, unsigned short* __restrict__ xT)
{
    const int b = blockIdx.z, c0 = blockIdx.y * 64, n0 = blockIdx.x * 64;
    const int t = threadIdx.x;
    __shared__ float Ls[64][65];
    const float* xb = x + ((size_t)b * C_ + c0) * N_ + n0;
#pragma unroll
    for (int i = 0; i < 4; i++) {
        int cc = (t >> 4) + 16 * i, n4 = (t & 15) * 4;
        float4 v = *(const float4*)(xb + (size_t)cc * N_ + n4);
        Ls[cc][n4 + 0] = v.x; Ls[cc][n4 + 1] = v.y;
        Ls[cc][n4 + 2] = v.z; Ls[cc][n4 + 3] = v.w;
    }
    __syncthreads();
    const int n = t >> 2, ce = (t & 3) * 16;
    ush8 o0, o1;
#pragma unroll
    for (int j = 0; j < 8; j++) o0[j] = f2bf(Ls[ce + j][n]);
#pragma unroll
    for (int j = 0; j < 8; j++) o1[j] = f2bf(Ls[ce + 8 + j][n]);
    unsigned short* dst = xT + ((size_t)b * N_ + n0 + n) * C_ + c0 + ce;
    *(ush8*)dst = o0;
    *(ush8*)(dst + 8) = o1;
}

// K2: projections, register-pipelined, swapped orientation (m = spatial n).
// D[n][r] = sum_c xT[n][c] * wbf[r][c]  -> tpg[r][n] written as ushort4 along n.
__global__ __launch_bounds__(256) void proj_mfma(
    const unsigned short* __restrict__ xT, const unsigned short* __restrict__ wbf,
    const float* __restrict__ tb, const float* __restrict__ pb,
    const float* __restrict__ gb, unsigned short* __restrict__ tpgbf)
{
    const int b = blockIdx.y, n0 = blockIdx.x * 32;
    const int t = threadIdx.x, w = t >> 6, L = t & 63;
    const int lr = L & 15, q = L >> 4;

    const unsigned short* aP0 = xT + ((size_t)b * N_ + n0 + lr) * 1024 + q * 8;
    const unsigned short* aP1 = aP0 + (size_t)16 * 1024;
    const unsigned short* bP0 = wbf + ((size_t)(48 * w + lr)) * 1024 + q * 8;
    const unsigned short* bP1 = bP0 + (size_t)16 * 1024;
    const unsigned short* bP2 = bP0 + (size_t)32 * 1024;

    f32x4 acc[2][3] = {};
    bf16x8 A0[2], A1[2], B0[2], B1[2], B2[2];
    A0[0] = *(const bf16x8*)(aP0);      A1[0] = *(const bf16x8*)(aP1);
    B0[0] = *(const bf16x8*)(bP0);      B1[0] = *(const bf16x8*)(bP1);
    B2[0] = *(const bf16x8*)(bP2);
    A0[1] = *(const bf16x8*)(aP0 + 32); A1[1] = *(const bf16x8*)(aP1 + 32);
    B0[1] = *(const bf16x8*)(bP0 + 32); B1[1] = *(const bf16x8*)(bP1 + 32);
    B2[1] = *(const bf16x8*)(bP2 + 32);

#pragma unroll
    for (int it = 0; it < 32; ++it) {
        const int cur = it & 1;
        bf16x8 a0 = A0[cur], a1 = A1[cur];
        bf16x8 b0 = B0[cur], b1 = B1[cur], b2 = B2[cur];
        if (it < 30) {
            const int kn = it * 32 + 64;
            A0[cur] = *(const bf16x8*)(aP0 + kn);
            A1[cur] = *(const bf16x8*)(aP1 + kn);
            B0[cur] = *(const bf16x8*)(bP0 + kn);
            B1[cur] = *(const bf16x8*)(bP1 + kn);
            B2[cur] = *(const bf16x8*)(bP2 + kn);
        }
        acc[0][0] = __builtin_amdgcn_mfma_f32_16x16x32_bf16(a0, b0, acc[0][0], 0, 0, 0);
        acc[0][1] = __builtin_amdgcn_mfma_f32_16x16x32_bf16(a0, b1, acc[0][1], 0, 0, 0);
        acc[0][2] = __builtin_amdgcn_mfma_f32_16x16x32_bf16(a0, b2, acc[0][2], 0, 0, 0);
        acc[1][0] = __builtin_amdgcn_mfma_f32_16x16x32_bf16(a1, b0, acc[1][0], 0, 0, 0);
        acc[1][1] = __builtin_amdgcn_mfma_f32_16x16x32_bf16(a1, b1, acc[1][1], 0, 0, 0);
        acc[1][2] = __builtin_amdgcn_mfma_f32_16x16x32_bf16(a1, b2, acc[1][2], 0, 0, 0);
    }

#pragma unroll
    for (int i = 0; i < 2; i++)
#pragma unroll
        for (int j = 0; j < 3; j++) {
            int rcol = 48 * w + 16 * j + lr;
            float bias = (rcol < 64) ? tb[rcol]
                       : (rcol < 128) ? pb[rcol - 64] : gb[rcol - 128];
            ush4 o;
#pragma unroll
            for (int rr = 0; rr < 4; rr++) o[rr] = f2bf(acc[i][j][rr] + bias);
            *(ush4*)(tpgbf + ((size_t)b * RTOT + rcol) * N_ + n0 + 16 * i + q * 4) = o;
        }
}

// K3: gram products via MFMA, register-pipelined, k-split (8 chunks) + atomics.
// p==0: M = phi·g^T ; p==1: G = theta·theta^T, plus S = theta·1 (ones MFMA)
__global__ __launch_bounds__(256) void gram_mfma(
    const unsigned short* __restrict__ tpgbf, float* __restrict__ Mm,
    float* __restrict__ Gg, float* __restrict__ S)
{
    const int kc = blockIdx.x, p = blockIdx.y, b = blockIdx.z;
    const int t = threadIdx.x, w = t >> 6, L = t & 63;
    const int lr = L & 15, q = L >> 4;
    const unsigned short* base = tpgbf + (size_t)b * RTOT * N_;
    const unsigned short* Arow = base + (p ? 0 : (size_t)64 * N_);
    const unsigned short* Brow = base + (p ? 0 : (size_t)128 * N_);
    const unsigned short* ap = Arow + ((size_t)(16 * w + lr)) * N_ + kc * 256 + q * 8;
    const unsigned short* bp = Brow + ((size_t)lr) * N_ + kc * 256 + q * 8;

    bf16x8 ones;
#pragma unroll
    for (int j = 0; j < 8; j++) ones[j] = (short)0x3F80;

    f32x4 acc[4] = {};
    f32x4 accs = {};
    bf16x8 Af[2], Bf[2][4];
    Af[0] = *(const bf16x8*)(ap);
    Af[1] = *(const bf16x8*)(ap + 32);
#pragma unroll
    for (int g = 0; g < 4; g++) {
        Bf[0][g] = *(const bf16x8*)(bp + (size_t)g * 16 * N_);
        Bf[1][g] = *(const bf16x8*)(bp + (size_t)g * 16 * N_ + 32);
    }
#pragma unroll
    for (int it = 0; it < 8; ++it) {
        const int cur = it & 1;
        bf16x8 a = Af[cur];
        bf16x8 bb0 = Bf[cur][0], bb1 = Bf[cur][1], bb2 = Bf[cur][2], bb3 = Bf[cur][3];
        if (it < 6) {
            const int kn = it * 32 + 64;
            Af[cur] = *(const bf16x8*)(ap + kn);
#pragma unroll
            for (int g = 0; g < 4; g++)
                Bf[cur][g] = *(const bf16x8*)(bp + (size_t)g * 16 * N_ + kn);
        }
        acc[0] = __builtin_amdgcn_mfma_f32_16x16x32_bf16(a, bb0, acc[0], 0, 0, 0);
        acc[1] = __builtin_amdgcn_mfma_f32_16x16x32_bf16(a, bb1, acc[1], 0, 0, 0);
        acc[2] = __builtin_amdgcn_mfma_f32_16x16x32_bf16(a, bb2, acc[2], 0, 0, 0);
        acc[3] = __builtin_amdgcn_mfma_f32_16x16x32_bf16(a, bb3, acc[3], 0, 0, 0);
        if (p) accs = __builtin_amdgcn_mfma_f32_16x16x32_bf16(a, ones, accs, 0, 0, 0);
    }
    float* outp = (p ? Gg : Mm) + (size_t)b * HID * HID;
#pragma unroll
    for (int g = 0; g < 4; g++)
#pragma unroll
        for (int r = 0; r < 4; r++) {
            int row = 16 * w + q * 4 + r, col = 16 * g + lr;
            atomicAdd(outp + row * HID + col, acc[g][r]);
        }
    if (p && lr == 0) {
#pragma unroll
        for (int r = 0; r < 4; r++)
            atomicAdd(S + b * HID + 16 * w + q * 4 + r, accs[r]);
    }
}

// K4: theta [e][n] bf16 -> thT [b][n][64] bf16
__global__ __launch_bounds__(256) void thT_k(
    const unsigned short* __restrict__ tpgbf, unsigned short* __restrict__ thT)
{
    const int b = blockIdx.y, n0 = blockIdx.x * 64;
    const int t = threadIdx.x;
    __shared__ unsigned short Ls[64][70];
    const unsigned short* src = tpgbf + (size_t)b * RTOT * N_ + n0;
    {
        int e = t >> 2, nc = (t & 3) * 16;
        ush8 v0 = *(const ush8*)(src + (size_t)e * N_ + nc);
        ush8 v1 = *(const ush8*)(src + (size_t)e * N_ + nc + 8);
#pragma unroll
        for (int j = 0; j < 8; j++) Ls[e][nc + j] = v0[j];
#pragma unroll
        for (int j = 0; j < 8; j++) Ls[e][nc + 8 + j] = v1[j];
    }
    __syncthreads();
    const int n = t >> 2, ec = (t & 3) * 16;
    ush8 o0, o1;
#pragma unroll
    for (int j = 0; j < 8; j++) o0[j] = Ls[ec + j][n];
#pragma unroll
    for (int j = 0; j < 8; j++) o1[j] = Ls[ec + 8 + j][n];
    unsigned short* dst = thT + ((size_t)b * N_ + n0 + n) * HID + ec;
    *(ush8*)dst = o0;
    *(ush8*)(dst + 8) = o1;
}

// K5: fused wmk + statsk. One block per channel c, 64 lanes = e.
__global__ __launch_bounds__(64) void wmstat(
    const float* __restrict__ ww, const float* __restrict__ Mm,
    const float* __restrict__ S, const float* __restrict__ G,
    const float* __restrict__ wb, const float* __restrict__ gamma,
    const float* __restrict__ beta, unsigned short* __restrict__ wmbf,
    float* __restrict__ scale, float* __restrict__ shift2)
{
    const int c = blockIdx.x, lane = threadIdx.x;
    const float wbc = wb[c];
    const float* wr = ww + (size_t)c * HID;   // uniform -> sgpr
    float asum = 0.f, asq = 0.f;
    for (int b = 0; b < B_; b++) {
        const float* mr = Mm + ((size_t)b * HID + lane) * HID;
        float acc = 0.f;
#pragma unroll
        for (int d = 0; d < HID; d += 4) {
            float4 m4 = *(const float4*)(mr + d);
            acc += wr[d] * m4.x + wr[d + 1] * m4.y + wr[d + 2] * m4.z + wr[d + 3] * m4.w;
        }
        unsigned short us = f2bf(acc * (1.0f / N_));
        wmbf[((size_t)b * C_ + c) * HID + lane] = us;
        float v = bf2f(us);
        float sv = S[b * HID + lane];
        float t1 = v * sv;
        for (int off = 32; off; off >>= 1) t1 += __shfl_down(t1, off);
        t1 = __shfl(t1, 0);
        const float* Gb = G + (size_t)b * HID * HID + (size_t)lane * HID;
        float inner = 0.f;
        for (int f = 0; f < HID; f++) inner = fmaf(Gb[f], __shfl(v, f), inner);
        float qq = v * inner;
        for (int off = 32; off; off >>= 1) qq += __shfl_down(qq, off);
        qq = __shfl(qq, 0);
        asum += t1;
        asq  += qq + 2.f * wbc * t1;
    }
    const float cnt = (float)B_ * (float)N_;
    const float inv = 1.0f / cnt;
    float mean = (asum + cnt * wbc) * inv;
    float e2   = (asq + cnt * wbc * wbc) * inv;
    float var  = e2 - mean * mean;
    float sc   = gamma[c] * rsqrtf(var + 1e-5f);
    if (lane == 0) {
        scale[c]  = sc;
        shift2[c] = beta[c] - mean * sc + sc * wbc;
    }
}

// K6: out = sc[c]*(Wm[b][c][:]·theta[:,n]) + sh[c] + x, swapped orientation:
// A = thT (m = spatial n), B = wmbf (cols = c) -> float4 stores along n.
__global__ __launch_bounds__(256) void finalk_mfma(
    const unsigned short* __restrict__ wmbf, const unsigned short* __restrict__ thT,
    const float* __restrict__ x, const float* __restrict__ scale,
    const float* __restrict__ shift2, float* __restrict__ out)
{
    const int b = blockIdx.z, c0 = blockIdx.y * 64, n0 = blockIdx.x * 64;
    const int t = threadIdx.x, w = t >> 6, L = t & 63;
    const int lr = L & 15, q = L >> 4;

    const unsigned short* ap = thT + ((size_t)b * N_ + n0 + 16 * w + lr) * HID + q * 8;
    const unsigned short* bp = wmbf + ((size_t)b * C_ + c0 + lr) * HID + q * 8;

    // prefetch residual x early (independent of MFMA pipeline)
    float4 xv[4];
    size_t xoff[4];
#pragma unroll
    for (int g = 0; g < 4; g++) {
        xoff[g] = ((size_t)b * C_ + c0 + 16 * g + lr) * N_ + n0 + 16 * w + q * 4;
        xv[g] = *(const float4*)(x + xoff[g]);
    }

    bf16x8 A0 = *(const bf16x8*)(ap);
    bf16x8 A1 = *(const bf16x8*)(ap + 32);
    f32x4 acc[4] = {};
#pragma unroll
    for (int g = 0; g < 4; g++) {
        bf16x8 Bg0 = *(const bf16x8*)(bp + (size_t)g * 16 * HID);
        bf16x8 Bg1 = *(const bf16x8*)(bp + (size_t)g * 16 * HID + 32);
        acc[g] = __builtin_amdgcn_mfma_f32_16x16x32_bf16(A0, Bg0, acc[g], 0, 0, 0);
        acc[g] = __builtin_amdgcn_mfma_f32_16x16x32_bf16(A1, Bg1, acc[g], 0, 0, 0);
    }
#pragma unroll
    for (int g = 0; g < 4; g++) {
        int c = c0 + 16 * g + lr;
        float sc = scale[c], sh = shift2[c];
        float4 o;
        o.x = fmaf(sc, acc[g][0], sh) + xv[g].x;
        o.y = fmaf(sc, acc[g][1], sh) + xv[g].y;
        o.z = fmaf(sc, acc[g][2], sh) + xv[g].z;
        o.w = fmaf(sc, acc[g][3], sh) + xv[g].w;
        *(float4*)(out + xoff[g]) = o;
    }
}

extern "C" void kernel_launch(void* const* d_in, const int* in_sizes, int n_in,
                              void* d_out, int out_size, void* d_ws, size_t ws_size,
                              hipStream_t stream)
{
    const float* x  = (const float*)d_in[0];
    const float* tw = (const float*)d_in[1];
    const float* tb = (const float*)d_in[2];
    const float* pw = (const float*)d_in[3];
    const float* pb = (const float*)d_in[4];
    const float* gw = (const float*)d_in[5];
    const float* gb = (const float*)d_in[6];
    const float* ww = (const float*)d_in[7];
    const float* wb = (const float*)d_in[8];
    const float* gamma = (const float*)d_in[9];
    const float* beta  = (const float*)d_in[10];
    float* out = (float*)d_out;

    char* ws = (char*)d_ws;
    unsigned short* xT    = (unsigned short*)(ws + WSB_XT);
    unsigned short* wbf   = (unsigned short*)(ws + WSB_WBF);
    unsigned short* tpgbf = (unsigned short*)(ws + WSB_TPG);
    unsigned short* thT   = (unsigned short*)(ws + WSB_THT);
    float* Mm   = (float*)(ws + WSB_M);
    float* Gg   = (float*)(ws + WSB_G);
    float* S    = (float*)(ws + WSB_S);
    unsigned short* wmbf = (unsigned short*)(ws + WSB_WMBF);
    float* scl  = (float*)(ws + WSB_SC);
    float* shf  = (float*)(ws + WSB_SH);

    // zero M, G, S (contiguous)
    hipMemsetAsync(Mm, 0, (size_t)(2 * B_ * HID * HID + B_ * HID) * sizeof(float), stream);

    wcvt<<<dim3(RTOT * 1024 / 256), 256, 0, stream>>>(tw, pw, gw, wbf);
    xT_k<<<dim3(32, 16, B_), 256, 0, stream>>>(x, xT);
    proj_mfma<<<dim3(64, B_), 256, 0, stream>>>(xT, wbf, tb, pb, gb, tpgbf);
    gram_mfma<<<dim3(8, 2, B_), 256, 0, stream>>>(tpgbf, Mm, Gg, S);
    thT_k<<<dim3(32, B_), 256, 0, stream>>>(tpgbf, thT);
    wmstat<<<C_, 64, 0, stream>>>(ww, Mm, S, Gg, wb, gamma, beta, wmbf, scl, shf);
    finalk_mfma<<<dim3(32, 16, B_), 256, 0, stream>>>(wmbf, thT, x, scl, shf, out);
}

// Round 4
// 220.239 us; speedup vs baseline: 1.8071x; 1.1052x over previous
//
#include <hip/hip_runtime.h>

#define B_    8
#define C_    1024
#define HID   64
#define N_    2048
#define RTOT  192

typedef __attribute__((ext_vector_type(8))) short   bf16x8;
typedef __attribute__((ext_vector_type(8))) unsigned short ush8;
typedef __attribute__((ext_vector_type(4))) unsigned short ush4;
typedef __attribute__((ext_vector_type(4))) float   f32x4;

// ---- workspace byte offsets ----
#define WSB_WBF   ((size_t)0)          // [192][1024]     bf16
#define WSB_TPG   ((size_t)393216)     // [B][192][2048]  bf16
#define WSB_THT   ((size_t)6684672)    // [B][2048][64]   bf16
#define WSB_M     ((size_t)8781824)    // [B][64][64]     f32
#define WSB_G     ((size_t)8912896)    // [B][64][64]     f32
#define WSB_S     ((size_t)9043968)    // [B][64]         f32 (contiguous after G)
#define WSB_WMBF  ((size_t)9046016)    // [B][1024][64]   bf16
#define WSB_SC    ((size_t)10094592)   // [1024] f32
#define WSB_SH    ((size_t)10098688)   // [1024] f32

static __device__ __forceinline__ unsigned short f2bf(float f) {
    union { float f; unsigned u; } v; v.f = f;
    unsigned r = v.u + 0x7fffu + ((v.u >> 16) & 1u);
    return (unsigned short)(r >> 16);
}
static __device__ __forceinline__ float bf2f(unsigned short h) {
    union { unsigned u; float f; } v; v.u = ((unsigned)h) << 16;
    return v.f;
}

// K0: weights -> bf16 (concat theta/phi/g)
__global__ __launch_bounds__(256) void wcvt(
    const float* __restrict__ tw, const float* __restrict__ pw,
    const float* __restrict__ gw, unsigned short* __restrict__ wbf)
{
    int idx = blockIdx.x * 256 + threadIdx.x;
    int r = idx >> 10, k = idx & 1023;
    float v = (r < 64) ? tw[(size_t)r * 1024 + k]
            : (r < 128) ? pw[(size_t)(r - 64) * 1024 + k]
                        : gw[(size_t)(r - 128) * 1024 + k];
    wbf[idx] = f2bf(v);
}

// K1: fused x-transpose + projection GEMM + theta-transpose output.
// Block: 32 spatial n x 192 outputs, full K=1024 in two LDS-staged halves.
// Inside each half the K-loop has NO barriers -> deep weight prefetch.
__global__ __launch_bounds__(256, 2) void proj_mfma(
    const float* __restrict__ x, const unsigned short* __restrict__ wbf,
    const float* __restrict__ tb, const float* __restrict__ pb,
    const float* __restrict__ gb, unsigned short* __restrict__ tpgbf,
    unsigned short* __restrict__ thT)
{
    const int b = blockIdx.y, n0 = blockIdx.x * 32;
    const int t = threadIdx.x, w = t >> 6, L = t & 63;
    const int lr = L & 15, q = L >> 4;
    __shared__ unsigned short A_lds[32][520];   // [n][k-half], pad 8: stride 1040B (16B-aligned, bank-clean)

    const float* xb = x + (size_t)b * C_ * N_ + n0;
    const unsigned short* bp = wbf + ((size_t)(48 * w + lr)) * 1024 + q * 8;

    f32x4 acc[2][3] = {};

#pragma unroll
    for (int ph = 0; ph < 2; ph++) {
        if (ph) __syncthreads();   // protect LDS reuse
        // ---- stage k-half [512*ph, 512*ph+512): transpose + cvt ----
#pragma unroll
        for (int i = 0; i < 8; i++) {
            int p = t + 256 * i;              // 0..2047
            int n4 = p & 7;                    // n-group of 4
            int c  = ((p >> 3) << 1);          // even c within half, 0..510
            f32x4 v0 = *(const f32x4*)(xb + (size_t)(512 * ph + c) * N_ + n4 * 4);
            f32x4 v1 = *(const f32x4*)(xb + (size_t)(512 * ph + c + 1) * N_ + n4 * 4);
#pragma unroll
            for (int r = 0; r < 4; r++) {
                unsigned val = (unsigned)f2bf(v0[r]) | ((unsigned)f2bf(v1[r]) << 16);
                *(unsigned*)&A_lds[n4 * 4 + r][c] = val;
            }
        }
        __syncthreads();
        // ---- barrier-free K-loop over this half ----
#pragma unroll
        for (int ks = 0; ks < 16; ks++) {
            const int kg = ph * 512 + ks * 32;
            bf16x8 B0 = *(const bf16x8*)(bp + kg);
            bf16x8 B1 = *(const bf16x8*)(bp + 16 * 1024 + kg);
            bf16x8 B2 = *(const bf16x8*)(bp + 32 * 1024 + kg);
            bf16x8 A0 = *(const bf16x8*)&A_lds[lr][ks * 32 + q * 8];
            bf16x8 A1 = *(const bf16x8*)&A_lds[16 + lr][ks * 32 + q * 8];
            acc[0][0] = __builtin_amdgcn_mfma_f32_16x16x32_bf16(A0, B0, acc[0][0], 0, 0, 0);
            acc[0][1] = __builtin_amdgcn_mfma_f32_16x16x32_bf16(A0, B1, acc[0][1], 0, 0, 0);
            acc[0][2] = __builtin_amdgcn_mfma_f32_16x16x32_bf16(A0, B2, acc[0][2], 0, 0, 0);
            acc[1][0] = __builtin_amdgcn_mfma_f32_16x16x32_bf16(A1, B0, acc[1][0], 0, 0, 0);
            acc[1][1] = __builtin_amdgcn_mfma_f32_16x16x32_bf16(A1, B1, acc[1][1], 0, 0, 0);
            acc[1][2] = __builtin_amdgcn_mfma_f32_16x16x32_bf16(A1, B2, acc[1][2], 0, 0, 0);
        }
    }

#pragma unroll
    for (int i = 0; i < 2; i++)
#pragma unroll
        for (int j = 0; j < 3; j++) {
            int rcol = 48 * w + 16 * j + lr;
            float bias = (rcol < 64) ? tb[rcol]
                       : (rcol < 128) ? pb[rcol - 64] : gb[rcol - 128];
            ush4 o;
#pragma unroll
            for (int rr = 0; rr < 4; rr++) o[rr] = f2bf(acc[i][j][rr] + bias);
            *(ush4*)(tpgbf + ((size_t)b * RTOT + rcol) * N_ + n0 + 16 * i + q * 4) = o;
            if (rcol < 64) {   // theta rows: also emit transposed copy for finalk
#pragma unroll
                for (int rr = 0; rr < 4; rr++)
                    thT[((size_t)b * N_ + n0 + 16 * i + q * 4 + rr) * HID + rcol] = o[rr];
            }
        }
}

// K2: gram products via MFMA, k-split (8 chunks) + atomics.
// p==0: M = phi·g^T ; p==1: G = theta·theta^T, plus S = theta·1
__global__ __launch_bounds__(256) void gram_mfma(
    const unsigned short* __restrict__ tpgbf, float* __restrict__ Mm,
    float* __restrict__ Gg, float* __restrict__ S)
{
    const int kc = blockIdx.x, p = blockIdx.y, b = blockIdx.z;
    const int t = threadIdx.x, w = t >> 6, L = t & 63;
    const int lr = L & 15, q = L >> 4;
    const unsigned short* base = tpgbf + (size_t)b * RTOT * N_;
    const unsigned short* Arow = base + (p ? 0 : (size_t)64 * N_);
    const unsigned short* Brow = base + (p ? 0 : (size_t)128 * N_);
    const unsigned short* ap = Arow + ((size_t)(16 * w + lr)) * N_ + kc * 256 + q * 8;
    const unsigned short* bp = Brow + ((size_t)lr) * N_ + kc * 256 + q * 8;

    bf16x8 ones;
#pragma unroll
    for (int j = 0; j < 8; j++) ones[j] = (short)0x3F80;

    f32x4 acc[4] = {};
    f32x4 accs = {};
#pragma unroll
    for (int it = 0; it < 8; ++it) {
        const int kn = it * 32;
        bf16x8 a = *(const bf16x8*)(ap + kn);
#pragma unroll
        for (int g = 0; g < 4; g++) {
            bf16x8 bb = *(const bf16x8*)(bp + (size_t)g * 16 * N_ + kn);
            acc[g] = __builtin_amdgcn_mfma_f32_16x16x32_bf16(a, bb, acc[g], 0, 0, 0);
        }
        if (p) accs = __builtin_amdgcn_mfma_f32_16x16x32_bf16(a, ones, accs, 0, 0, 0);
    }
    float* outp = (p ? Gg : Mm) + (size_t)b * HID * HID;
#pragma unroll
    for (int g = 0; g < 4; g++)
#pragma unroll
        for (int r = 0; r < 4; r++) {
            int row = 16 * w + q * 4 + r, col = 16 * g + lr;
            atomicAdd(outp + row * HID + col, acc[g][r]);
        }
    if (p && lr == 0) {
#pragma unroll
        for (int r = 0; r < 4; r++)
            atomicAdd(S + b * HID + 16 * w + q * 4 + r, accs[r]);
    }
}

// K3: fused wmk + statsk. One block per channel c, 64 lanes = e.
__global__ __launch_bounds__(64) void wmstat(
    const float* __restrict__ ww, const float* __restrict__ Mm,
    const float* __restrict__ S, const float* __restrict__ G,
    const float* __restrict__ wb, const float* __restrict__ gamma,
    const float* __restrict__ beta, unsigned short* __restrict__ wmbf,
    float* __restrict__ scale, float* __restrict__ shift2)
{
    const int c = blockIdx.x, lane = threadIdx.x;
    const float wbc = wb[c];
    const float* wr = ww + (size_t)c * HID;
    float asum = 0.f, asq = 0.f;
    for (int b = 0; b < B_; b++) {
        const float* mr = Mm + ((size_t)b * HID + lane) * HID;
        float acc = 0.f;
#pragma unroll
        for (int d = 0; d < HID; d += 4) {
            float4 m4 = *(const float4*)(mr + d);
            acc += wr[d] * m4.x + wr[d + 1] * m4.y + wr[d + 2] * m4.z + wr[d + 3] * m4.w;
        }
        unsigned short us = f2bf(acc * (1.0f / N_));
        wmbf[((size_t)b * C_ + c) * HID + lane] = us;
        float v = bf2f(us);
        float sv = S[b * HID + lane];
        float t1 = v * sv;
        for (int off = 32; off; off >>= 1) t1 += __shfl_down(t1, off);
        t1 = __shfl(t1, 0);
        const float* Gb = G + (size_t)b * HID * HID + (size_t)lane * HID;
        float inner = 0.f;
        for (int f = 0; f < HID; f++) inner = fmaf(Gb[f], __shfl(v, f), inner);
        float qq = v * inner;
        for (int off = 32; off; off >>= 1) qq += __shfl_down(qq, off);
        qq = __shfl(qq, 0);
        asum += t1;
        asq  += qq + 2.f * wbc * t1;
    }
    const float cnt = (float)B_ * (float)N_;
    const float inv = 1.0f / cnt;
    float mean = (asum + cnt * wbc) * inv;
    float e2   = (asq + cnt * wbc * wbc) * inv;
    float var  = e2 - mean * mean;
    float sc   = gamma[c] * rsqrtf(var + 1e-5f);
    if (lane == 0) {
        scale[c]  = sc;
        shift2[c] = beta[c] - mean * sc + sc * wbc;
    }
}

// K4: out = sc[c]*(Wm[b][c][:]·theta[:,n]) + sh[c] + x  (float4 stores along n)
__global__ __launch_bounds__(256) void finalk_mfma(
    const unsigned short* __restrict__ wmbf, const unsigned short* __restrict__ thT,
    const float* __restrict__ x, const float* __restrict__ scale,
    const float* __restrict__ shift2, float* __restrict__ out)
{
    const int b = blockIdx.z, c0 = blockIdx.y * 64, n0 = blockIdx.x * 64;
    const int t = threadIdx.x, w = t >> 6, L = t & 63;
    const int lr = L & 15, q = L >> 4;

    const unsigned short* ap = thT + ((size_t)b * N_ + n0 + 16 * w + lr) * HID + q * 8;
    const unsigned short* bp = wmbf + ((size_t)b * C_ + c0 + lr) * HID + q * 8;

    float4 xv[4];
    size_t xoff[4];
#pragma unroll
    for (int g = 0; g < 4; g++) {
        xoff[g] = ((size_t)b * C_ + c0 + 16 * g + lr) * N_ + n0 + 16 * w + q * 4;
        xv[g] = *(const float4*)(x + xoff[g]);
    }

    bf16x8 A0 = *(const bf16x8*)(ap);
    bf16x8 A1 = *(const bf16x8*)(ap + 32);
    f32x4 acc[4] = {};
#pragma unroll
    for (int g = 0; g < 4; g++) {
        bf16x8 Bg0 = *(const bf16x8*)(bp + (size_t)g * 16 * HID);
        bf16x8 Bg1 = *(const bf16x8*)(bp + (size_t)g * 16 * HID + 32);
        acc[g] = __builtin_amdgcn_mfma_f32_16x16x32_bf16(A0, Bg0, acc[g], 0, 0, 0);
        acc[g] = __builtin_amdgcn_mfma_f32_16x16x32_bf16(A1, Bg1, acc[g], 0, 0, 0);
    }
#pragma unroll
    for (int g = 0; g < 4; g++) {
        int c = c0 + 16 * g + lr;
        float sc = scale[c], sh = shift2[c];
        float4 o;
        o.x = fmaf(sc, acc[g][0], sh) + xv[g].x;
        o.y = fmaf(sc, acc[g][1], sh) + xv[g].y;
        o.z = fmaf(sc, acc[g][2], sh) + xv[g].z;
        o.w = fmaf(sc, acc[g][3], sh) + xv[g].w;
        *(float4*)(out + xoff[g]) = o;
    }
}

extern "C" void kernel_launch(void* const* d_in, const int* in_sizes, int n_in,
                              void* d_out, int out_size, void* d_ws, size_t ws_size,
                              hipStream_t stream)
{
    const float* x  = (const float*)d_in[0];
    const float* tw = (const float*)d_in[1];
    const float* tb = (const float*)d_in[2];
    const float* pw = (const float*)d_in[3];
    const float* pb = (const float*)d_in[4];
    const float* gw = (const float*)d_in[5];
    const float* gb = (const float*)d_in[6];
    const float* ww = (const float*)d_in[7];
    const float* wb = (const float*)d_in[8];
    const float* gamma = (const float*)d_in[9];
    const float* beta  = (const float*)d_in[10];
    float* out = (float*)d_out;

    char* ws = (char*)d_ws;
    unsigned short* wbf   = (unsigned short*)(ws + WSB_WBF);
    unsigned short* tpgbf = (unsigned short*)(ws + WSB_TPG);
    unsigned short* thT   = (unsigned short*)(ws + WSB_THT);
    float* Mm   = (float*)(ws + WSB_M);
    float* Gg   = (float*)(ws + WSB_G);
    float* S    = (float*)(ws + WSB_S);
    unsigned short* wmbf = (unsigned short*)(ws + WSB_WMBF);
    float* scl  = (float*)(ws + WSB_SC);
    float* shf  = (float*)(ws + WSB_SH);

    // zero M, G, S (contiguous)
    hipMemsetAsync(Mm, 0, (size_t)(2 * B_ * HID * HID + B_ * HID) * sizeof(float), stream);

    wcvt<<<dim3(RTOT * 1024 / 256), 256, 0, stream>>>(tw, pw, gw, wbf);
    proj_mfma<<<dim3(64, B_), 256, 0, stream>>>(x, wbf, tb, pb, gb, tpgbf, thT);
    gram_mfma<<<dim3(8, 2, B_), 256, 0, stream>>>(tpgbf, Mm, Gg, S);
    wmstat<<<C_, 64, 0, stream>>>(ww, Mm, S, Gg, wb, gamma, beta, wmbf, scl, shf);
    finalk_mfma<<<dim3(32, 16, B_), 256, 0, stream>>>(wmbf, thT, x, scl, shf, out);
}